// Round 1
// baseline (271.446 us; speedup 1.0000x reference)
//
#include <hip/hip_runtime.h>
#include <math.h>

#define NRES 126  // N in the reference; NRES % 3 == 0

// One NeRF extension step, exactly mirroring the reference:
//   bc = normalize(b - c + 1e-8)
//   n  = normalize(cross(b - a, bc) + 1e-8)
//   m1 = cross(n, bc)
//   d  = c + rot0*bc + rot1*m1 + rot2*n
// rot0 = bond*cos(alpha); rot1 = bond*sin(alpha)*cos_t; rot2 = -bond*sin(alpha)*sin_t
__device__ __forceinline__ void nerf_step(
    float s, float co,            // raw sin_t, cos_t (unnormalized)
    float rc, float bs,           // bond*cos(alpha), bond*sin(alpha)
    float &ax, float &ay, float &az,
    float &bx, float &by, float &bz,
    float &cx, float &cy, float &cz,
    float &dx, float &dy, float &dz)
{
    // normalize the (sin, cos) pair: n_t = sqrt(s^2 + c^2 + 1e-8)
    float nt  = sqrtf(s * s + co * co + 1e-8f);
    float rnt = 1.0f / nt;             // nt >= 1e-4, always safe
    s  *= rnt;
    co *= rnt;
    float r1 =  bs * co;               // bond*sin_a*cos_t
    float r2 = -(bs * s);              // -bond*sin_a*sin_t

    // bc = normalize(b - c + 1e-8)
    float ux = bx - cx + 1e-8f;
    float uy = by - cy + 1e-8f;
    float uz = bz - cz + 1e-8f;
    float du = ux * ux + uy * uy + uz * uz;
    float ru = 1.0f / fmaxf(sqrtf(du), 1e-12f);
    ux *= ru; uy *= ru; uz *= ru;

    // n = normalize(cross(b - a, bc) + 1e-8)
    float vx = bx - ax;
    float vy = by - ay;
    float vz = bz - az;
    float nx = vy * uz - vz * uy + 1e-8f;
    float ny = vz * ux - vx * uz + 1e-8f;
    float nz = vx * uy - vy * ux + 1e-8f;
    float dn = nx * nx + ny * ny + nz * nz;
    float rn = 1.0f / fmaxf(sqrtf(dn), 1e-12f);
    nx *= rn; ny *= rn; nz *= rn;

    // m1 = cross(n, bc)
    float mx = ny * uz - nz * uy;
    float my = nz * ux - nx * uz;
    float mz = nx * uy - ny * ux;

    // d = c + rc*bc + r1*m1 + r2*n
    dx = cx + rc * ux + r1 * mx + r2 * nx;
    dy = cy + rc * uy + r1 * my + r2 * ny;
    dz = cz + rc * uz + r1 * mz + r2 * nz;

    // shift carry: (a,b,c) <- (b,c,d)
    ax = bx; ay = by; az = bz;
    bx = cx; by = cy; bz = cz;
    cx = dx; cy = dy; cz = dz;
}

__global__ __launch_bounds__(256) void DihedralToCartesian_kernel(
    const float* __restrict__ angles,   // (B, 2*NRES)
    const float* __restrict__ prev,     // (B, 3, 3)
    float* __restrict__ out,            // (B, NRES, 3)
    int nrows)
{
    int b = blockIdx.x * blockDim.x + threadIdx.x;
    if (b >= nrows) return;

    const float* ar   = angles + (size_t)b * (2 * NRES);
    const float* pr   = prev   + (size_t)b * 9;
    float*       orow = out    + (size_t)b * (3 * NRES);

    float ax = pr[0], ay = pr[1], az = pr[2];
    float bx = pr[3], by = pr[4], bz = pr[5];
    float cx = pr[6], cy = pr[7], cz = pr[8];

    // 3-periodic alpha/bond constants (computed once per thread, f32 like the ref)
    const float alpha0 = 2.028f, alpha1 = 2.124f, alpha2 = 1.941f;
    const float bond0  = 1.329f, bond1  = 1.458f, bond2  = 1.523f;
    const float rc0 = bond0 * cosf(alpha0), bs0 = bond0 * sinf(alpha0);
    const float rc1 = bond1 * cosf(alpha1), bs1 = bond1 * sinf(alpha1);
    const float rc2 = bond2 * cosf(alpha2), bs2 = bond2 * sinf(alpha2);

    float dx, dy, dz;
    for (int i = 0; i < NRES; i += 3) {
        // k = 0 (mod 3)
        {
            float s = ar[i], c = ar[NRES + i];
            nerf_step(s, c, rc0, bs0, ax, ay, az, bx, by, bz, cx, cy, cz, dx, dy, dz);
            orow[3 * i + 0] = dx; orow[3 * i + 1] = dy; orow[3 * i + 2] = dz;
        }
        // k = 1
        {
            float s = ar[i + 1], c = ar[NRES + i + 1];
            nerf_step(s, c, rc1, bs1, ax, ay, az, bx, by, bz, cx, cy, cz, dx, dy, dz);
            orow[3 * (i + 1) + 0] = dx; orow[3 * (i + 1) + 1] = dy; orow[3 * (i + 1) + 2] = dz;
        }
        // k = 2
        {
            float s = ar[i + 2], c = ar[NRES + i + 2];
            nerf_step(s, c, rc2, bs2, ax, ay, az, bx, by, bz, cx, cy, cz, dx, dy, dz);
            orow[3 * (i + 2) + 0] = dx; orow[3 * (i + 2) + 1] = dy; orow[3 * (i + 2) + 2] = dz;
        }
    }
}

extern "C" void kernel_launch(void* const* d_in, const int* in_sizes, int n_in,
                              void* d_out, int out_size, void* d_ws, size_t ws_size,
                              hipStream_t stream)
{
    const float* angles = (const float*)d_in[0];
    const float* prev   = (const float*)d_in[1];
    float*       out    = (float*)d_out;

    int nrows = in_sizes[1] / 9;   // B
    int block = 256;
    int grid  = (nrows + block - 1) / block;

    DihedralToCartesian_kernel<<<grid, block, 0, stream>>>(angles, prev, out, nrows);
}

// Round 2
// 199.418 us; speedup vs baseline: 1.3612x; 1.3612x over previous
//
#include <hip/hip_runtime.h>
#include <math.h>

#define NRES   126          // steps per row
#define CHUNK  21           // steps per staged chunk; 126 = 6*21, 21%3==0
#define NCHUNK (NRES / CHUNK)
#define ROWS   256          // rows per block == blockDim.x
#define OUTF   (3 * CHUNK)  // 63 output floats per thread per chunk

// One NeRF extension step, exactly mirroring the reference math (f32).
__device__ __forceinline__ void nerf_step(
    float s, float co,            // raw sin_t, cos_t (unnormalized)
    float rc, float bs,           // bond*cos(alpha), bond*sin(alpha)
    float &ax, float &ay, float &az,
    float &bx, float &by, float &bz,
    float &cx, float &cy, float &cz,
    float &dx, float &dy, float &dz)
{
    float nt  = sqrtf(s * s + co * co + 1e-8f);
    float rnt = 1.0f / nt;
    s  *= rnt;
    co *= rnt;
    float r1 =  bs * co;
    float r2 = -(bs * s);

    // bc = normalize(b - c + 1e-8)
    float ux = bx - cx + 1e-8f;
    float uy = by - cy + 1e-8f;
    float uz = bz - cz + 1e-8f;
    float du = ux * ux + uy * uy + uz * uz;
    float ru = 1.0f / fmaxf(sqrtf(du), 1e-12f);
    ux *= ru; uy *= ru; uz *= ru;

    // n = normalize(cross(b - a, bc) + 1e-8)
    float vx = bx - ax;
    float vy = by - ay;
    float vz = bz - az;
    float nx = vy * uz - vz * uy + 1e-8f;
    float ny = vz * ux - vx * uz + 1e-8f;
    float nz = vx * uy - vy * ux + 1e-8f;
    float dn = nx * nx + ny * ny + nz * nz;
    float rn = 1.0f / fmaxf(sqrtf(dn), 1e-12f);
    nx *= rn; ny *= rn; nz *= rn;

    // m1 = cross(n, bc)
    float mx = ny * uz - nz * uy;
    float my = nz * ux - nx * uz;
    float mz = nx * uy - ny * ux;

    // d = c + rc*bc + r1*m1 + r2*n
    dx = cx + rc * ux + r1 * mx + r2 * nx;
    dy = cy + rc * uy + r1 * my + r2 * ny;
    dz = cz + rc * uz + r1 * mz + r2 * nz;

    ax = bx; ay = by; az = bz;
    bx = cx; by = cy; bz = cz;
    cx = dx; cy = dy; cz = dz;
}

__global__ __launch_bounds__(256, 1) void DihedralToCartesian_kernel(
    const float* __restrict__ angles,   // (B, 2*NRES): [0:126)=sin, [126:252)=cos
    const float* __restrict__ prev,     // (B, 3, 3)
    float* __restrict__ out,            // (B, NRES, 3)
    int nrows)
{
    // LDS staging: sin/cos slabs (row-major [r][j], flat) + output slab.
    __shared__ float s_sin[ROWS * CHUNK];   // 21 KB
    __shared__ float s_cos[ROWS * CHUNK];   // 21 KB
    __shared__ float s_out[ROWS * OUTF];    // 64.5 KB  -> 107.5 KB total

    const int t  = threadIdx.x;
    const int b0 = blockIdx.x * ROWS;       // first row of this block
    const int row = b0 + t;

    // ---- carry from prev_three (small, strided; one-time) ----
    const float* pr = prev + (size_t)row * 9;
    float ax = pr[0], ay = pr[1], az = pr[2];
    float bx = pr[3], by = pr[4], bz = pr[5];
    float cx = pr[6], cy = pr[7], cz = pr[8];

    // 3-periodic constants (folded at compile time)
    const float rc0 = 1.329f * cosf(2.028f), bs0 = 1.329f * sinf(2.028f);
    const float rc1 = 1.458f * cosf(2.124f), bs1 = 1.458f * sinf(2.124f);
    const float rc2 = 1.523f * cosf(1.941f), bs2 = 1.523f * sinf(1.941f);

    // ---- prologue: coalesced prefetch of chunk 0 into registers ----
    // Flat element space over [r in 0..ROWS) x [j in 0..CHUNK): idx = p*ROWS + t.
    float As[CHUNK], Ac[CHUNK];
    #pragma unroll
    for (int p = 0; p < CHUNK; ++p) {
        int idx = p * ROWS + t;
        int r   = idx / CHUNK;
        int j   = idx - r * CHUNK;
        const float* g = angles + (size_t)(b0 + r) * (2 * NRES);
        As[p] = g[j];            // sin half, cols [0..CHUNK)
        Ac[p] = g[NRES + j];     // cos half
    }

    for (int k = 0; k < NCHUNK; ++k) {
        const int i0 = k * CHUNK;

        __syncthreads();   // (a) LDS buffers free (prev chunk fully consumed)

        // regs -> LDS (linear store, conflict-free)
        #pragma unroll
        for (int p = 0; p < CHUNK; ++p) {
            s_sin[p * ROWS + t] = As[p];
            s_cos[p * ROWS + t] = Ac[p];
        }

        __syncthreads();   // (b) sin/cos slab ready

        // async prefetch of next chunk into registers; HBM latency hides
        // under the 21-step dependent chain below.
        if (k + 1 < NCHUNK) {
            const int i0n = i0 + CHUNK;
            #pragma unroll
            for (int p = 0; p < CHUNK; ++p) {
                int idx = p * ROWS + t;
                int r   = idx / CHUNK;
                int j   = idx - r * CHUNK;
                const float* g = angles + (size_t)(b0 + r) * (2 * NRES) + i0n;
                As[p] = g[j];
                Ac[p] = g[NRES + j];
            }
        }

        // ---- compute 21 steps; outputs stay in registers (static-indexed) ----
        float o[OUTF];
        float dx, dy, dz;
        #pragma unroll
        for (int j = 0; j < CHUNK; ++j) {
            float s  = s_sin[t * CHUNK + j];   // lane stride 21 (odd): 2-way max, free
            float co = s_cos[t * CHUNK + j];
            const int ph = j % 3;              // i0 % 3 == 0, so phase = j % 3 (compile-time)
            const float rc = (ph == 0) ? rc0 : (ph == 1) ? rc1 : rc2;
            const float bs = (ph == 0) ? bs0 : (ph == 1) ? bs1 : bs2;
            nerf_step(s, co, rc, bs, ax, ay, az, bx, by, bz, cx, cy, cz, dx, dy, dz);
            o[3 * j + 0] = dx;
            o[3 * j + 1] = dy;
            o[3 * j + 2] = dz;
        }

        // stage outputs in LDS (lane stride 63, odd -> conflict-free)
        #pragma unroll
        for (int q = 0; q < OUTF; ++q)
            s_out[t * OUTF + q] = o[q];

        __syncthreads();   // (d) out slab ready

        // coalesced global store: consecutive lanes write consecutive floats
        #pragma unroll
        for (int p = 0; p < OUTF; ++p) {
            int idx = p * ROWS + t;
            int r   = idx / OUTF;
            int jj  = idx - r * OUTF;
            out[(size_t)(b0 + r) * (3 * NRES) + (size_t)i0 * 3 + jj] = s_out[idx];
        }
    }
}

extern "C" void kernel_launch(void* const* d_in, const int* in_sizes, int n_in,
                              void* d_out, int out_size, void* d_ws, size_t ws_size,
                              hipStream_t stream)
{
    const float* angles = (const float*)d_in[0];
    const float* prev   = (const float*)d_in[1];
    float*       out    = (float*)d_out;

    int nrows = in_sizes[1] / 9;        // B (65536; divisible by ROWS)
    int grid  = nrows / ROWS;

    DihedralToCartesian_kernel<<<grid, ROWS, 0, stream>>>(angles, prev, out, nrows);
}

// Round 3
// 176.274 us; speedup vs baseline: 1.5399x; 1.1313x over previous
//
#include <hip/hip_runtime.h>
#include <math.h>

#define NRES   126          // steps per row
#define CHUNK  21           // steps per staged chunk; 126 = 6*21, 21%3==0
#define NCHUNK (NRES / CHUNK)
#define ROWS   64           // rows per block == blockDim.x (1 wave -> decoupled phases)
#define OUTF   (3 * CHUNK)  // 63 output floats per thread per chunk

// 1/max(sqrt(x),1e-12) == rsqrt(max(x,1e-24))  (sqrt monotone); rsq ~1 ulp.
__device__ __forceinline__ float guarded_rsqrt(float x) {
    return __builtin_amdgcn_rsqf(fmaxf(x, 1e-24f));
}

// One NeRF extension step, mirroring the reference math (f32, approx rsqrt).
__device__ __forceinline__ void nerf_step(
    float s, float co,            // raw sin_t, cos_t (unnormalized)
    float rc, float bs,           // bond*cos(alpha), bond*sin(alpha)
    float &ax, float &ay, float &az,
    float &bx, float &by, float &bz,
    float &cx, float &cy, float &cz,
    float &dx, float &dy, float &dz)
{
    // n_t = sqrt(s^2 + c^2 + 1e-8)  ->  rnt = rsqrt(...)  (arg >= 1e-8, no guard)
    float rnt = __builtin_amdgcn_rsqf(s * s + co * co + 1e-8f);
    s  *= rnt;
    co *= rnt;
    float r1 =  bs * co;
    float r2 = -(bs * s);

    // bc = normalize(b - c + 1e-8)
    float ux = bx - cx + 1e-8f;
    float uy = by - cy + 1e-8f;
    float uz = bz - cz + 1e-8f;
    float ru = guarded_rsqrt(ux * ux + uy * uy + uz * uz);
    ux *= ru; uy *= ru; uz *= ru;

    // n = normalize(cross(b - a, bc) + 1e-8)
    float vx = bx - ax;
    float vy = by - ay;
    float vz = bz - az;
    float nx = vy * uz - vz * uy + 1e-8f;
    float ny = vz * ux - vx * uz + 1e-8f;
    float nz = vx * uy - vy * ux + 1e-8f;
    float rn = guarded_rsqrt(nx * nx + ny * ny + nz * nz);
    nx *= rn; ny *= rn; nz *= rn;

    // m1 = cross(n, bc)
    float mx = ny * uz - nz * uy;
    float my = nz * ux - nx * uz;
    float mz = nx * uy - ny * ux;

    // d = c + rc*bc + r1*m1 + r2*n
    dx = cx + rc * ux + r1 * mx + r2 * nx;
    dy = cy + rc * uy + r1 * my + r2 * ny;
    dz = cz + rc * uz + r1 * mz + r2 * nz;

    ax = bx; ay = by; az = bz;
    bx = cx; by = cy; bz = cz;
    cx = dx; cy = dy; cz = dz;
}

__global__ __launch_bounds__(ROWS, 1) void DihedralToCartesian_kernel(
    const float* __restrict__ angles,   // (B, 2*NRES): [0:126)=sin, [126:252)=cos
    const float* __restrict__ prev,     // (B, 3, 3)
    float* __restrict__ out,            // (B, NRES, 3)
    int nrows)
{
    __shared__ float s_sin[ROWS * CHUNK];   // 5.25 KB
    __shared__ float s_cos[ROWS * CHUNK];   // 5.25 KB
    __shared__ float s_out[ROWS * OUTF];    // 15.75 KB -> 26.25 KB/block, 4 blocks/CU

    const int t   = threadIdx.x;
    const int b0  = blockIdx.x * ROWS;
    const int row = b0 + t;

    const float* pr = prev + (size_t)row * 9;
    float ax = pr[0], ay = pr[1], az = pr[2];
    float bx = pr[3], by = pr[4], bz = pr[5];
    float cx = pr[6], cy = pr[7], cz = pr[8];

    // 3-periodic constants (folded at compile time)
    const float rc0 = 1.329f * cosf(2.028f), bs0 = 1.329f * sinf(2.028f);
    const float rc1 = 1.458f * cosf(2.124f), bs1 = 1.458f * sinf(2.124f);
    const float rc2 = 1.523f * cosf(1.941f), bs2 = 1.523f * sinf(1.941f);

    // Prologue: coalesced prefetch of chunk 0 into registers.
    // Flat space [r in 0..ROWS) x [j in 0..CHUNK): idx = p*ROWS + t.
    float As[CHUNK], Ac[CHUNK];
    #pragma unroll
    for (int p = 0; p < CHUNK; ++p) {
        int idx = p * ROWS + t;
        int r   = idx / CHUNK;
        int j   = idx - r * CHUNK;
        const float* g = angles + (size_t)(b0 + r) * (2 * NRES);
        As[p] = g[j];
        Ac[p] = g[NRES + j];
    }

    for (int k = 0; k < NCHUNK; ++k) {
        const int i0 = k * CHUNK;

        __syncthreads();   // LDS buffers free (single-wave: cheap)

        #pragma unroll
        for (int p = 0; p < CHUNK; ++p) {
            s_sin[p * ROWS + t] = As[p];
            s_cos[p * ROWS + t] = Ac[p];
        }

        __syncthreads();   // slab ready

        // Prefetch next chunk into registers; latency hides under the 21-step chain.
        if (k + 1 < NCHUNK) {
            const int i0n = i0 + CHUNK;
            #pragma unroll
            for (int p = 0; p < CHUNK; ++p) {
                int idx = p * ROWS + t;
                int r   = idx / CHUNK;
                int j   = idx - r * CHUNK;
                const float* g = angles + (size_t)(b0 + r) * (2 * NRES) + i0n;
                As[p] = g[j];
                Ac[p] = g[NRES + j];
            }
        }

        // 21 steps; outputs to registers (static-indexed).
        float o[OUTF];
        float dx, dy, dz;
        #pragma unroll
        for (int j = 0; j < CHUNK; ++j) {
            float s  = s_sin[t * CHUNK + j];   // stride 21 (odd): conflict-free
            float co = s_cos[t * CHUNK + j];
            const int ph = j % 3;              // compile-time (loop fully unrolled)
            const float rc = (ph == 0) ? rc0 : (ph == 1) ? rc1 : rc2;
            const float bs = (ph == 0) ? bs0 : (ph == 1) ? bs1 : bs2;
            nerf_step(s, co, rc, bs, ax, ay, az, bx, by, bz, cx, cy, cz, dx, dy, dz);
            o[3 * j + 0] = dx;
            o[3 * j + 1] = dy;
            o[3 * j + 2] = dz;
        }

        #pragma unroll
        for (int q = 0; q < OUTF; ++q)
            s_out[t * OUTF + q] = o[q];        // stride 63 (odd): conflict-free

        __syncthreads();   // out slab ready

        // Coalesced global store.
        #pragma unroll
        for (int p = 0; p < OUTF; ++p) {
            int idx = p * ROWS + t;
            int r   = idx / OUTF;
            int jj  = idx - r * OUTF;
            out[(size_t)(b0 + r) * (3 * NRES) + (size_t)i0 * 3 + jj] = s_out[idx];
        }
    }
}

extern "C" void kernel_launch(void* const* d_in, const int* in_sizes, int n_in,
                              void* d_out, int out_size, void* d_ws, size_t ws_size,
                              hipStream_t stream)
{
    const float* angles = (const float*)d_in[0];
    const float* prev   = (const float*)d_in[1];
    float*       out    = (float*)d_out;

    int nrows = in_sizes[1] / 9;        // B = 65536, divisible by ROWS
    int grid  = nrows / ROWS;           // 1024 blocks of 1 wave each

    DihedralToCartesian_kernel<<<grid, ROWS, 0, stream>>>(angles, prev, out, nrows);
}